// Round 3
// baseline (85.413 us; speedup 1.0000x reference)
//
#include <hip/hip_runtime.h>

// DepthLossV2: sum over lower triangle (i>=j) of piecewise penalty on
// d0 = p[i]-p[j], s = (i-j)*a, a = STEP*z_spacing*nth_slice:
//   d0 < 0           -> -d0
//   0 <= d0 < 0.2s   -> 0.2s - d0
//   else             -> max(d0 - s, 0)
// For d0 >= 0 this is exactly max3(0.2s - d0, d0 - s, 0)  (one v_max3_f32).
// Triangular mask j<=i  <=>  s>=0 (a>0, s exact: integers*10 < 2^24).
// loss = sum / (n*n)
//
// Single fused kernel: block partial -> device atomicAdd(double) into ws
// accumulator; last-arriving block (device-scope counter) writes d_out.
// ws is poisoned 0xAA before every launch (harness contract), so the
// counter starts at 0xAAAAAAAAu and the accumulator at a known double
// bit-pattern — no zero-init pass needed.

constexpr int ROWS = 256;   // threads per block, one i-row each
constexpr int COLS = 128;   // j-extent per block
constexpr unsigned POISON_U32 = 0xAAAAAAAAu;

__global__ __launch_bounds__(ROWS) void depth_loss_kernel(
    const float* __restrict__ p,
    const float* __restrict__ zsp,
    const float* __restrict__ nsl,
    double* __restrict__ acc_ws,      // ws[0]: double accumulator (poisoned)
    unsigned* __restrict__ counter,   // ws[8..11]: completion counter (poisoned)
    float* __restrict__ out,
    double inv_nn, double poison_dbl, unsigned nblocks)
{
    // block b -> (ri, cj): row-tile ri has 2*ri+2 col-tiles, prefix = ri*(ri+1)
    int b = blockIdx.x;
    int ri = (int)((sqrtf(4.0f * (float)b + 1.0f) - 1.0f) * 0.5f);
    while ((ri + 1) * (ri + 2) <= b) ++ri;
    while (ri * (ri + 1) > b) --ri;
    int cj = b - ri * (ri + 1);

    int tid = threadIdx.x;
    int i = ri * ROWS + tid;
    float pi = p[i];

    __shared__ __align__(16) float pj[COLS];
    int jbase = cj * COLS;
    if (tid < COLS / 4)
        ((float4*)pj)[tid] = ((const float4*)(p + jbase))[tid];
    __syncthreads();

    float a   = zsp[0] * nsl[0];   // STEP == 1.0, a > 0
    float a02 = 0.2f * a;
    float s   = (float)(i - jbase) * a;   // s for j = jbase, decremented per col
    float s02 = 0.2f * s;

    float acc = 0.0f;
    const float4* pj4 = (const float4*)pj;

#define PAIR_BODY(PJV, MASKED)                                   \
    {                                                            \
        float d0 = pi - (PJV);                                   \
        float n0 = (PJV) - pi;                                   \
        float e1 = s02 - d0;                                     \
        float e2 = d0 - s;                                       \
        float m  = fmaxf(fmaxf(e1, e2), 0.0f); /* v_max3 */      \
        float c  = (d0 < 0.0f) ? n0 : m;                         \
        if (MASKED) c = (s >= 0.0f) ? c : 0.0f;                  \
        acc += c;                                                \
        s   -= a;                                                \
        s02 -= a02;                                              \
    }

    if (cj < 2 * ri) {
        #pragma unroll 8
        for (int q = 0; q < COLS / 4; ++q) {
            float4 v = pj4[q];
            PAIR_BODY(v.x, false)
            PAIR_BODY(v.y, false)
            PAIR_BODY(v.z, false)
            PAIR_BODY(v.w, false)
        }
    } else {
        #pragma unroll 8
        for (int q = 0; q < COLS / 4; ++q) {
            float4 v = pj4[q];
            PAIR_BODY(v.x, true)
            PAIR_BODY(v.y, true)
            PAIR_BODY(v.z, true)
            PAIR_BODY(v.w, true)
        }
    }
#undef PAIR_BODY

    // wave-64 shuffle reduction
    for (int off = 32; off > 0; off >>= 1)
        acc += __shfl_down(acc, off, 64);

    __shared__ float wsum[ROWS / 64];
    if ((tid & 63) == 0) wsum[tid >> 6] = acc;
    __syncthreads();

    if (tid == 0) {
        float blocksum = 0.0f;
        for (int w = 0; w < ROWS / 64; ++w) blocksum += wsum[w];
        atomicAdd(acc_ws, (double)blocksum);       // device-scope
        __threadfence();                           // publish before counting
        unsigned old = atomicAdd(counter, 1u);
        if (old == POISON_U32 + nblocks - 1u) {    // last block done
            __threadfence();
            double total = atomicAdd(acc_ws, 0.0); // atomic read (coherent)
            out[0] = (float)((total - poison_dbl) * inv_nn);
        }
    }
}

extern "C" void kernel_launch(void* const* d_in, const int* in_sizes, int n_in,
                              void* d_out, int out_size, void* d_ws, size_t ws_size,
                              hipStream_t stream) {
    const float* p   = (const float*)d_in[0];
    const float* zsp = (const float*)d_in[1];
    const float* nsl = (const float*)d_in[2];
    float* out = (float*)d_out;
    double* acc_ws = (double*)d_ws;
    unsigned* counter = (unsigned*)((char*)d_ws + 8);

    int n = in_sizes[0];            // 8192, divisible by ROWS
    int nrt = (n + ROWS - 1) / ROWS;
    unsigned nblocks = (unsigned)(nrt * (nrt + 1));  // sum of (2*ri+2)
    double inv_nn = 1.0 / ((double)n * (double)n);

    unsigned long long pbits = 0xAAAAAAAAAAAAAAAAull;
    double poison_dbl;
    __builtin_memcpy(&poison_dbl, &pbits, sizeof(double));

    depth_loss_kernel<<<nblocks, ROWS, 0, stream>>>(
        p, zsp, nsl, acc_ws, counter, out, inv_nn, poison_dbl, nblocks);
}

// Round 4
// 68.283 us; speedup vs baseline: 1.2509x; 1.2509x over previous
//
#include <hip/hip_runtime.h>

// DepthLossV2: sum over lower triangle (i>=j) of piecewise penalty on
// d0 = p[i]-p[j], s = (i-j)*a, a = STEP*z_spacing*nth_slice:
//   d0 < 0           -> -d0
//   0 <= d0 < 0.2s   -> 0.2s - d0
//   else             -> max(d0 - s, 0)
// With n0 = pj - pi and dij = i-j (float, exact):
//   e1 = 0.2s - d0 = fma(dij, 0.2a, n0)
//   t  = s    - d0... wait: s + n0 = s - d0  ->  d0 - s = -t
//   c  = (n0 > 0) ? n0 : max3(e1, -t, 0)
// 8 VALU ops/pair. Mask j<=i <=> dij>=0 (boundary tiles only, 64/1056).
// loss = sum / (n*n)
//
// Two kernels (round-3 lesson: fused same-line atomic completion cost ~15us;
// the tiny finalize kernel is cheaper).

constexpr int ROWS = 256;   // threads per block, one i-row each
constexpr int COLS = 128;   // j-extent per block

__global__ __launch_bounds__(ROWS) void depth_loss_kernel(
    const float* __restrict__ p,
    const float* __restrict__ zsp,
    const float* __restrict__ nsl,
    double* __restrict__ partials)
{
    // block b -> (ri, cj): row-tile ri has 2*ri+2 col-tiles, prefix = ri*(ri+1)
    int b = blockIdx.x;
    int ri = (int)((sqrtf(4.0f * (float)b + 1.0f) - 1.0f) * 0.5f);
    while ((ri + 1) * (ri + 2) <= b) ++ri;
    while (ri * (ri + 1) > b) --ri;
    int cj = b - ri * (ri + 1);

    int tid = threadIdx.x;
    int i = ri * ROWS + tid;
    float pi = p[i];

    __shared__ __align__(16) float pj[COLS];
    int jbase = cj * COLS;
    if (tid < COLS / 4)
        ((float4*)pj)[tid] = ((const float4*)(p + jbase))[tid];
    __syncthreads();

    float a   = zsp[0] * nsl[0];   // STEP == 1.0, a > 0
    float a02 = 0.2f * a;
    float dij = (float)(i - jbase);   // i - j at j=jbase; -=1 per col; exact

    float acc0 = 0.0f, acc1 = 0.0f;
    const float4* pj4 = (const float4*)pj;

#define PAIR_BODY(PJV, ACC, MASKED)                                \
    {                                                              \
        float n0 = (PJV) - pi;                                     \
        float e1 = __builtin_fmaf(dij, a02, n0); /* 0.2s - d0 */   \
        float t  = __builtin_fmaf(dij, a,   n0); /* s - d0    */   \
        float cp = fmaxf(fmaxf(e1, -t), 0.0f);   /* v_max3    */   \
        float c  = (n0 > 0.0f) ? n0 : cp;                          \
        if (MASKED) c = (dij >= 0.0f) ? c : 0.0f;                  \
        ACC += c;                                                  \
        dij -= 1.0f;                                               \
    }

    if (cj < 2 * ri) {
        // fully interior: every j in tile <= every i in tile
        #pragma unroll 8
        for (int q = 0; q < COLS / 4; ++q) {
            float4 v = pj4[q];
            PAIR_BODY(v.x, acc0, false)
            PAIR_BODY(v.y, acc1, false)
            PAIR_BODY(v.z, acc0, false)
            PAIR_BODY(v.w, acc1, false)
        }
    } else {
        // boundary tile: mask j > i via sign of dij
        #pragma unroll 8
        for (int q = 0; q < COLS / 4; ++q) {
            float4 v = pj4[q];
            PAIR_BODY(v.x, acc0, true)
            PAIR_BODY(v.y, acc1, true)
            PAIR_BODY(v.z, acc0, true)
            PAIR_BODY(v.w, acc1, true)
        }
    }
#undef PAIR_BODY

    float acc = acc0 + acc1;

    // wave-64 shuffle reduction
    for (int off = 32; off > 0; off >>= 1)
        acc += __shfl_down(acc, off, 64);

    __shared__ float wsum[ROWS / 64];
    if ((tid & 63) == 0) wsum[tid >> 6] = acc;
    __syncthreads();

    if (tid == 0) {
        float blocksum = 0.0f;
        for (int w = 0; w < ROWS / 64; ++w) blocksum += wsum[w];
        partials[blockIdx.x] = (double)blocksum;
    }
}

__global__ __launch_bounds__(256) void finalize_kernel(
    const double* __restrict__ partials, int nblocks, float* __restrict__ out,
    double inv_nn)
{
    int tid = threadIdx.x;
    double acc = 0.0;
    for (int b = tid; b < nblocks; b += 256) acc += partials[b];
    for (int off = 32; off > 0; off >>= 1)
        acc += __shfl_down(acc, off, 64);
    __shared__ double wsum[4];
    if ((tid & 63) == 0) wsum[tid >> 6] = acc;
    __syncthreads();
    if (tid == 0)
        out[0] = (float)((wsum[0] + wsum[1] + wsum[2] + wsum[3]) * inv_nn);
}

extern "C" void kernel_launch(void* const* d_in, const int* in_sizes, int n_in,
                              void* d_out, int out_size, void* d_ws, size_t ws_size,
                              hipStream_t stream) {
    const float* p   = (const float*)d_in[0];
    const float* zsp = (const float*)d_in[1];
    const float* nsl = (const float*)d_in[2];
    float* out = (float*)d_out;
    double* partials = (double*)d_ws;

    int n = in_sizes[0];            // 8192, divisible by ROWS
    int nrt = (n + ROWS - 1) / ROWS;
    int nblocks = nrt * (nrt + 1);  // sum of (2*ri+2), ri=0..nrt-1
    double inv_nn = 1.0 / ((double)n * (double)n);

    depth_loss_kernel<<<nblocks, ROWS, 0, stream>>>(p, zsp, nsl, partials);
    finalize_kernel<<<1, 256, 0, stream>>>(partials, nblocks, out, inv_nn);
}

// Round 5
// 68.011 us; speedup vs baseline: 1.2559x; 1.0040x over previous
//
#include <hip/hip_runtime.h>

// DepthLossV2: sum over lower triangle (i>=j) of piecewise penalty on
// d0 = p[i]-p[j], s = (i-j)*a, a = STEP*z_spacing*nth_slice:
//   d0 < 0           -> -d0
//   0 <= d0 < 0.2s   -> 0.2s - d0
//   else             -> max(d0 - s, 0)
// With n0 = pj - pi and dij = i-j (float, exact):
//   e1 = fma(dij, 0.2a, n0)   (= 0.2s - d0)
//   t  = fma(dij, a,   n0)    (= s - d0)
//   c  = (n0 > 0) ? n0 : max3(e1, -t, 0)
// Packed f32 (v_pk_fma_f32 / v_pk_add_f32 via v2f32 elementwise ops) does
// 2 pairs per instruction for sub/fma/add; max3+select stay scalar.
// Mask j<=i <=> dij>=0, needed only in diagonal-touching tiles.
// loss = sum / (n*n)

typedef float f32x2 __attribute__((ext_vector_type(2)));

constexpr int ROWS = 256;   // threads per block, one i-row each
constexpr int COLS = 64;    // j-extent per block (8.25 blocks/CU, small tail)

__global__ __launch_bounds__(ROWS) void depth_loss_kernel(
    const float* __restrict__ p,
    const float* __restrict__ zsp,
    const float* __restrict__ nsl,
    double* __restrict__ partials)
{
    // block b -> (ri, cj): row-tile ri has 4*ri+4 col-tiles, prefix = 2*ri*(ri+1)
    int b = blockIdx.x;
    int ri = (int)((sqrtf(2.0f * (float)b + 1.0f) - 1.0f) * 0.5f);
    while (2 * (ri + 1) * (ri + 2) <= b) ++ri;
    while (2 * ri * (ri + 1) > b) --ri;
    int cj = b - 2 * ri * (ri + 1);

    int tid = threadIdx.x;
    int i = ri * ROWS + tid;
    float pi = p[i];

    __shared__ __align__(16) float pj[COLS];
    int jbase = cj * COLS;
    if (tid < COLS / 4)
        ((float4*)pj)[tid] = ((const float4*)(p + jbase))[tid];
    __syncthreads();

    float a   = zsp[0] * nsl[0];   // STEP == 1.0, a > 0
    float a02 = 0.2f * a;
    f32x2 av   = { a,   a   };
    f32x2 a02v = { a02, a02 };
    f32x2 four = { 4.0f, 4.0f };
    f32x2 zero = { 0.0f, 0.0f };
    f32x2 pi2  = { pi, pi };

    float dij0 = (float)(i - jbase);          // exact in float
    f32x2 d2a = { dij0,        dij0 - 1.0f }; // pairs (x,y)
    f32x2 d2b = { dij0 - 2.0f, dij0 - 3.0f }; // pairs (z,w)

    f32x2 acc2a = zero, acc2b = zero;
    const float4* pj4 = (const float4*)pj;

#define GROUP_BODY(VA, D2, ACC, MASKED)                               \
    {                                                                 \
        f32x2 n0 = (VA) - pi2;                      /* v_pk_add  */   \
        f32x2 e1 = __builtin_elementwise_fma(D2, a02v, n0);           \
        f32x2 t  = __builtin_elementwise_fma(D2, av,   n0);           \
        f32x2 cp = __builtin_elementwise_max(                         \
                       __builtin_elementwise_max(e1, -t), zero);      \
        f32x2 c;                                                      \
        c.x = (n0.x > 0.0f) ? n0.x : cp.x;                            \
        c.y = (n0.y > 0.0f) ? n0.y : cp.y;                            \
        if (MASKED) {                                                 \
            c.x = (D2.x >= 0.0f) ? c.x : 0.0f;                        \
            c.y = (D2.y >= 0.0f) ? c.y : 0.0f;                        \
        }                                                             \
        ACC += c;                                    /* v_pk_add */   \
        D2  -= four;                                 /* v_pk_add */   \
    }

    if (cj < 4 * ri) {
        // fully interior: every j in tile < every i in tile
        #pragma unroll
        for (int q = 0; q < COLS / 4; ++q) {
            float4 v = pj4[q];
            f32x2 va = { v.x, v.y };
            f32x2 vb = { v.z, v.w };
            GROUP_BODY(va, d2a, acc2a, false)
            GROUP_BODY(vb, d2b, acc2b, false)
        }
    } else {
        // diagonal-touching tile: mask j > i via sign of dij
        #pragma unroll
        for (int q = 0; q < COLS / 4; ++q) {
            float4 v = pj4[q];
            f32x2 va = { v.x, v.y };
            f32x2 vb = { v.z, v.w };
            GROUP_BODY(va, d2a, acc2a, true)
            GROUP_BODY(vb, d2b, acc2b, true)
        }
    }
#undef GROUP_BODY

    float acc = (acc2a.x + acc2a.y) + (acc2b.x + acc2b.y);

    // wave-64 shuffle reduction
    for (int off = 32; off > 0; off >>= 1)
        acc += __shfl_down(acc, off, 64);

    __shared__ float wsum[ROWS / 64];
    if ((tid & 63) == 0) wsum[tid >> 6] = acc;
    __syncthreads();

    if (tid == 0) {
        float blocksum = 0.0f;
        for (int w = 0; w < ROWS / 64; ++w) blocksum += wsum[w];
        partials[blockIdx.x] = (double)blocksum;
    }
}

__global__ __launch_bounds__(256) void finalize_kernel(
    const double* __restrict__ partials, int nblocks, float* __restrict__ out,
    double inv_nn)
{
    int tid = threadIdx.x;
    double acc = 0.0;
    for (int b = tid; b < nblocks; b += 256) acc += partials[b];
    for (int off = 32; off > 0; off >>= 1)
        acc += __shfl_down(acc, off, 64);
    __shared__ double wsum[4];
    if ((tid & 63) == 0) wsum[tid >> 6] = acc;
    __syncthreads();
    if (tid == 0)
        out[0] = (float)((wsum[0] + wsum[1] + wsum[2] + wsum[3]) * inv_nn);
}

extern "C" void kernel_launch(void* const* d_in, const int* in_sizes, int n_in,
                              void* d_out, int out_size, void* d_ws, size_t ws_size,
                              hipStream_t stream) {
    const float* p   = (const float*)d_in[0];
    const float* zsp = (const float*)d_in[1];
    const float* nsl = (const float*)d_in[2];
    float* out = (float*)d_out;
    double* partials = (double*)d_ws;

    int n = in_sizes[0];              // 8192, divisible by ROWS
    int nrt = (n + ROWS - 1) / ROWS;
    int nblocks = 2 * nrt * (nrt + 1);  // sum of (4*ri+4), ri=0..nrt-1
    double inv_nn = 1.0 / ((double)n * (double)n);

    depth_loss_kernel<<<nblocks, ROWS, 0, stream>>>(p, zsp, nsl, partials);
    finalize_kernel<<<1, 256, 0, stream>>>(partials, nblocks, out, inv_nn);
}